// Round 3
// baseline (653.384 us; speedup 1.0000x reference)
//
#include <hip/hip_runtime.h>
#include <hip/hip_bf16.h>
#include <cstdint>

// Set2Set forward, 3 steps. N=200000, B=1024 segments, D=256.
// ALL float tensors are FLOAT32 on device (per reference dtypes); batch int32.
// Round 3: f32 I/O. LSTM GEMM via MFMA with bf16 hi/lo split of both
// operands (3 MFMAs/k-step -> ~2^-17 relative accuracy). Attention split
// into 3 kernels (dot / norm / acc) with kernel-boundary ordering.

#define NN     200000
#define BSEG   1024
#define DD     256
#define KA     768     // 2D (q_star) + D (h)
#define FOURD  1024

using bf16x8 = __attribute__((ext_vector_type(8))) __bf16;
using f32x4  = __attribute__((ext_vector_type(4))) float;

__device__ __forceinline__ float bf2f(unsigned int u) {
  union { unsigned int i; float f; } v; v.i = (u & 0xffffu) << 16; return v.f;
}
__device__ __forceinline__ unsigned short f2bf(float f) {
  union { float f; unsigned int i; } v; v.f = f;
  unsigned int x = v.i;
  if ((x & 0x7fffffffu) > 0x7f800000u) return (unsigned short)((x >> 16) | 0x40);
  return (unsigned short)((x + 0x7fffu + ((x >> 16) & 1u)) >> 16);
}
// split f32 into bf16 hi + bf16 lo (hi+lo ~ f32 to ~2^-17 rel)
__device__ __forceinline__ void split_bf(float f, unsigned short& hi, unsigned short& lo) {
  hi = f2bf(f);
  lo = f2bf(f - bf2f(hi));
}

// ---- prep kernels --------------------------------------------------------

// seg_start[b] = first i with batch[i] >= b (batch sorted), b in [0, BSEG]
__global__ void seg_bounds(const int* __restrict__ batch, int* __restrict__ segs) {
  int b = blockIdx.x * blockDim.x + threadIdx.x;
  if (b > BSEG) return;
  int lo = 0, hi = NN;
  while (lo < hi) { int mid = (lo + hi) >> 1; if (batch[mid] < b) lo = mid + 1; else hi = mid; }
  segs[b] = lo;
}

// Wcat[j][0:512]=W_ih[j], Wcat[j][512:768]=W_hh[j] as bf16 hi/lo; bias=b_ih+b_hh
__global__ void prep_wcat(const float* __restrict__ Wih,
                          const float* __restrict__ Whh,
                          const float* __restrict__ bih,
                          const float* __restrict__ bhh,
                          unsigned short* __restrict__ Whi,
                          unsigned short* __restrict__ Wlo,
                          float* __restrict__ bias) {
  int idx = blockIdx.x * 256 + threadIdx.x;      // 1024*768
  if (idx < FOURD * KA) {
    int j = idx / KA, k = idx - j * KA;
    float w = (k < 512) ? Wih[j * 512 + k] : Whh[j * 256 + (k - 512)];
    unsigned short hi, lo; split_bf(w, hi, lo);
    Whi[idx] = hi; Wlo[idx] = lo;
  }
  if (idx < FOURD) bias[idx] = bih[idx] + bhh[idx];
}

// A[b][0:512]=q_star (hi/lo), A[b][512:768]=h=0; h,c=0
__global__ void prep_A(const float* __restrict__ qst,
                       unsigned short* __restrict__ Ahi,
                       unsigned short* __restrict__ Alo,
                       float* __restrict__ h, float* __restrict__ c) {
  int idx = blockIdx.x * 256 + threadIdx.x;      // 1024*768
  if (idx >= BSEG * KA) return;
  int b = idx / KA, k = idx - b * KA;
  unsigned short hi = 0, lo = 0;
  if (k < 512) split_bf(qst[b * 512 + k], hi, lo);
  Ahi[idx] = hi; Alo[idx] = lo;
  if (k >= 512) { h[b * DD + (k - 512)] = 0.f; c[b * DD + (k - 512)] = 0.f; }
}

// ---- LSTM gates GEMM: gates = (Ahi+Alo) @ (Whi+Wlo)^T --------------------
// wave-per-16x16 tile. A frag: A[m=lane&15][k=quad*8+j]; B frag (B^T input):
// W[n=lane&15][k=quad*8+j]; D: col=lane&15, row=quad*4+r.
__global__ __launch_bounds__(256) void gemm_gates(const unsigned short* __restrict__ Ahi,
                                                  const unsigned short* __restrict__ Alo,
                                                  const unsigned short* __restrict__ Whi,
                                                  const unsigned short* __restrict__ Wlo,
                                                  float* __restrict__ gates) {
  int wave = (blockIdx.x << 2) | (threadIdx.x >> 6);
  int lane = threadIdx.x & 63;
  int m0 = (wave >> 6) << 4;
  int n0 = (wave & 63) << 4;
  int r16 = lane & 15, quad = lane >> 4;
  const unsigned short* ap  = Ahi + (size_t)(m0 + r16) * KA + quad * 8;
  const unsigned short* alp = Alo + (size_t)(m0 + r16) * KA + quad * 8;
  const unsigned short* bp  = Whi + (size_t)(n0 + r16) * KA + quad * 8;
  const unsigned short* blp = Wlo + (size_t)(n0 + r16) * KA + quad * 8;
  f32x4 acc = {0.f, 0.f, 0.f, 0.f};
  for (int k = 0; k < KA; k += 32) {
    bf16x8 a  = *(const bf16x8*)(ap + k);
    bf16x8 al = *(const bf16x8*)(alp + k);
    bf16x8 b  = *(const bf16x8*)(bp + k);
    bf16x8 bl = *(const bf16x8*)(blp + k);
    acc = __builtin_amdgcn_mfma_f32_16x16x32_bf16(a,  b,  acc, 0, 0, 0);
    acc = __builtin_amdgcn_mfma_f32_16x16x32_bf16(a,  bl, acc, 0, 0, 0);
    acc = __builtin_amdgcn_mfma_f32_16x16x32_bf16(al, b,  acc, 0, 0, 0);
  }
  #pragma unroll
  for (int r = 0; r < 4; ++r)
    gates[(size_t)(m0 + quad * 4 + r) * FOURD + n0 + r16] = acc[r];
}

// ---- LSTM pointwise: gate order i,f,g,o ----------------------------------
__global__ __launch_bounds__(256) void lstm_pointwise(const float* __restrict__ gates,
                                                      const float* __restrict__ bias,
                                                      float* __restrict__ h,
                                                      float* __restrict__ c,
                                                      unsigned short* __restrict__ Ahi,
                                                      unsigned short* __restrict__ Alo,
                                                      float* __restrict__ qout) {
  int idx = blockIdx.x * 256 + threadIdx.x;      // B*D
  int b = idx >> 8, d = idx & 255;
  const float* g = gates + (size_t)b * FOURD;
  float gi = g[d]       + bias[d];
  float gf = g[256 + d] + bias[256 + d];
  float gg = g[512 + d] + bias[512 + d];
  float go = g[768 + d] + bias[768 + d];
  float ig = 1.f / (1.f + expf(-gi));
  float fg = 1.f / (1.f + expf(-gf));
  float gt = tanhf(gg);
  float og = 1.f / (1.f + expf(-go));
  float cn = fg * c[idx] + ig * gt;
  float hn = og * tanhf(cn);
  c[idx] = cn; h[idx] = hn;
  unsigned short hi, lo; split_bf(hn, hi, lo);
  size_t ro = (size_t)b * KA;
  Ahi[ro + d] = hi;        Alo[ro + d] = lo;        // q_star q-part [0,256)
  Ahi[ro + 512 + d] = hi;  Alo[ro + 512 + d] = lo;  // h-part [512,768)
  qout[(size_t)b * 512 + d] = hn;                   // output q half
}

// ---- attention kernel 1: e[i] = x[i] . h[batch[i]] -----------------------
// 4 waves/block, wave per node; lane covers 4 channels. Covers ALL i.
__global__ __launch_bounds__(256) void attn_dot(const float* __restrict__ x,
                                                const int* __restrict__ batch,
                                                const float* __restrict__ h,
                                                float* __restrict__ e) {
  int i = blockIdx.x * 4 + (threadIdx.x >> 6);
  if (i >= NN) return;
  int lane = threadIdx.x & 63;
  int b = batch[i];
  float4 q  = *(const float4*)(h + (size_t)b * DD + lane * 4);
  float4 xv = *(const float4*)(x + (size_t)i * DD + lane * 4);
  float d = xv.x * q.x + xv.y * q.y + xv.z * q.z + xv.w * q.w;
  #pragma unroll
  for (int off = 32; off; off >>= 1) d += __shfl_down(d, off);
  if (lane == 0) e[i] = d;
}

// ---- attention kernel 2: per-segment max, e[i] <- exp(e-m), denom --------
__global__ __launch_bounds__(256) void attn_norm(const int* __restrict__ segs,
                                                 float* __restrict__ e,
                                                 float* __restrict__ dnm) {
  int b = blockIdx.x, t = threadIdx.x;
  int s = segs[b], tend = segs[b + 1];
  __shared__ float sred[256];
  float lm = -3.402823466e38f;
  for (int i = s + t; i < tend; i += 256) lm = fmaxf(lm, e[i]);
  sred[t] = lm; __syncthreads();
  #pragma unroll
  for (int st = 128; st; st >>= 1) {
    if (t < st) sred[t] = fmaxf(sred[t], sred[t + st]);
    __syncthreads();
  }
  float m = sred[0];
  if (m < -1e37f) m = 0.f;              // mirror reference isfinite guard
  __syncthreads();
  float ls = 0.f;
  for (int i = s + t; i < tend; i += 256) {
    float ee = expf(e[i] - m);
    e[i] = ee;
    ls += ee;
  }
  sred[t] = ls; __syncthreads();
  #pragma unroll
  for (int st = 128; st; st >>= 1) {
    if (t < st) sred[t] += sred[t + st];
    __syncthreads();
  }
  if (t == 0) dnm[b] = sred[0];
}

// ---- attention kernel 3: r[b][t] = sum_i ee_i*x[i][t] / denom ------------
__global__ __launch_bounds__(256) void attn_acc(const float* __restrict__ x,
                                                const int* __restrict__ segs,
                                                const float* __restrict__ e,
                                                const float* __restrict__ dnm,
                                                unsigned short* __restrict__ Ahi,
                                                unsigned short* __restrict__ Alo,
                                                float* __restrict__ qout) {
  int b = blockIdx.x, t = threadIdx.x;
  int s = segs[b], tend = segs[b + 1];
  float inv = 1.f / (dnm[b] + 1e-16f);
  float a0 = 0.f, a1 = 0.f;
  int i = s;
  for (; i + 2 <= tend; i += 2) {
    a0 += e[i]     * x[(size_t)i * DD + t];
    a1 += e[i + 1] * x[(size_t)(i + 1) * DD + t];
  }
  if (i < tend) a0 += e[i] * x[(size_t)i * DD + t];
  float r = (a0 + a1) * inv;
  unsigned short hi, lo; split_bf(r, hi, lo);
  size_t ro = (size_t)b * KA;
  Ahi[ro + DD + t] = hi;  Alo[ro + DD + t] = lo;    // q_star r-part [256,512)
  qout[(size_t)b * 512 + DD + t] = r;               // output r half
}

// ---- launch --------------------------------------------------------------
extern "C" void kernel_launch(void* const* d_in, const int* in_sizes, int n_in,
                              void* d_out, int out_size, void* d_ws, size_t ws_size,
                              hipStream_t stream) {
  const float* x    = (const float*)d_in[0];
  const int*   batc = (const int*)d_in[2];
  const float* qst  = (const float*)d_in[3];
  const float* Wih  = (const float*)d_in[4];
  const float* Whh  = (const float*)d_in[5];
  const float* bih  = (const float*)d_in[6];
  const float* bhh  = (const float*)d_in[7];
  float* out = (float*)d_out;

  char* ws = (char*)d_ws;
  size_t off = 0;
  auto alloc = [&](size_t bytes) -> void* {
    void* p = ws + off; off = (off + bytes + 255) & ~(size_t)255; return p;
  };
  float*          e    = (float*)alloc((size_t)NN * 4);
  int*            segs = (int*)alloc((size_t)(BSEG + 1) * 4);
  float*          dnm  = (float*)alloc((size_t)BSEG * 4);
  unsigned short* Whi  = (unsigned short*)alloc((size_t)FOURD * KA * 2);
  unsigned short* Wlo  = (unsigned short*)alloc((size_t)FOURD * KA * 2);
  unsigned short* Ahi  = (unsigned short*)alloc((size_t)BSEG * KA * 2);
  unsigned short* Alo  = (unsigned short*)alloc((size_t)BSEG * KA * 2);
  float*          gate = (float*)alloc((size_t)BSEG * FOURD * 4);
  float*          h    = (float*)alloc((size_t)BSEG * DD * 4);
  float*          c    = (float*)alloc((size_t)BSEG * DD * 4);
  float*          bias = (float*)alloc((size_t)FOURD * 4);

  seg_bounds<<<5, 256, 0, stream>>>(batc, segs);
  prep_wcat<<<(FOURD * KA + 255) / 256, 256, 0, stream>>>(Wih, Whh, bih, bhh, Whi, Wlo, bias);
  prep_A<<<(BSEG * KA + 255) / 256, 256, 0, stream>>>(qst, Ahi, Alo, h, c);

  for (int step = 0; step < 3; ++step) {
    gemm_gates<<<1024, 256, 0, stream>>>(Ahi, Alo, Whi, Wlo, gate);
    lstm_pointwise<<<BSEG * DD / 256, 256, 0, stream>>>(gate, bias, h, c, Ahi, Alo, out);
    attn_dot<<<(NN + 3) / 4, 256, 0, stream>>>(x, batc, h, e);
    attn_norm<<<BSEG, 256, 0, stream>>>(segs, e, dnm);
    attn_acc<<<BSEG, 256, 0, stream>>>(x, segs, e, dnm, Ahi, Alo, out);
  }
}

// Round 4
// 525.600 us; speedup vs baseline: 1.2431x; 1.2431x over previous
//
#include <hip/hip_runtime.h>
#include <hip/hip_bf16.h>
#include <cstdint>

// Set2Set forward, 3 steps. N=200000, B=1024 segments, D=256. All f32 I/O.
// Round 4: one-pass online-softmax attention (wave-local state, merge at
// end) -> x read once per step (600 MB total vs 1.2 GB); 9 launches vs 21.
// LSTM GEMM unchanged (MFMA bf16 hi/lo split, proven absmax 2e-3).

#define NN     200000
#define BSEG   1024
#define DD     256
#define KA     768     // 2D (q_star) + D (h)
#define FOURD  1024

using bf16x8 = __attribute__((ext_vector_type(8))) __bf16;
using f32x4  = __attribute__((ext_vector_type(4))) float;

__device__ __forceinline__ float bf2f(unsigned int u) {
  union { unsigned int i; float f; } v; v.i = (u & 0xffffu) << 16; return v.f;
}
__device__ __forceinline__ unsigned short f2bf(float f) {
  union { float f; unsigned int i; } v; v.f = f;
  unsigned int x = v.i;
  if ((x & 0x7fffffffu) > 0x7f800000u) return (unsigned short)((x >> 16) | 0x40);
  return (unsigned short)((x + 0x7fffu + ((x >> 16) & 1u)) >> 16);
}
__device__ __forceinline__ void split_bf(float f, unsigned short& hi, unsigned short& lo) {
  hi = f2bf(f);
  lo = f2bf(f - bf2f(hi));
}

// ---- prep kernels --------------------------------------------------------

__global__ void seg_bounds(const int* __restrict__ batch, int* __restrict__ segs) {
  int b = blockIdx.x * blockDim.x + threadIdx.x;
  if (b > BSEG) return;
  int lo = 0, hi = NN;
  while (lo < hi) { int mid = (lo + hi) >> 1; if (batch[mid] < b) lo = mid + 1; else hi = mid; }
  segs[b] = lo;
}

__global__ void prep_wcat(const float* __restrict__ Wih,
                          const float* __restrict__ Whh,
                          const float* __restrict__ bih,
                          const float* __restrict__ bhh,
                          unsigned short* __restrict__ Whi,
                          unsigned short* __restrict__ Wlo,
                          float* __restrict__ bias) {
  int idx = blockIdx.x * 256 + threadIdx.x;      // 1024*768
  if (idx < FOURD * KA) {
    int j = idx / KA, k = idx - j * KA;
    float w = (k < 512) ? Wih[j * 512 + k] : Whh[j * 256 + (k - 512)];
    unsigned short hi, lo; split_bf(w, hi, lo);
    Whi[idx] = hi; Wlo[idx] = lo;
  }
  if (idx < FOURD) bias[idx] = bih[idx] + bhh[idx];
}

__global__ void prep_A(const float* __restrict__ qst,
                       unsigned short* __restrict__ Ahi,
                       unsigned short* __restrict__ Alo,
                       float* __restrict__ h, float* __restrict__ c) {
  int idx = blockIdx.x * 256 + threadIdx.x;      // 1024*768
  if (idx >= BSEG * KA) return;
  int b = idx / KA, k = idx - b * KA;
  unsigned short hi = 0, lo = 0;
  if (k < 512) split_bf(qst[b * 512 + k], hi, lo);
  Ahi[idx] = hi; Alo[idx] = lo;
  if (k >= 512) { h[b * DD + (k - 512)] = 0.f; c[b * DD + (k - 512)] = 0.f; }
}

// ---- LSTM gates GEMM: gates = (Ahi+Alo) @ (Whi+Wlo)^T --------------------
// wave-per-16x16 tile. A frag: A[m=lane&15][k=quad*8+j]; B frag (B^T input):
// W[n=lane&15][k=quad*8+j]; D: col=lane&15, row=quad*4+r.
__global__ __launch_bounds__(256) void gemm_gates(const unsigned short* __restrict__ Ahi,
                                                  const unsigned short* __restrict__ Alo,
                                                  const unsigned short* __restrict__ Whi,
                                                  const unsigned short* __restrict__ Wlo,
                                                  float* __restrict__ gates) {
  int wave = (blockIdx.x << 2) | (threadIdx.x >> 6);
  int lane = threadIdx.x & 63;
  int m0 = (wave >> 6) << 4;
  int n0 = (wave & 63) << 4;
  int r16 = lane & 15, quad = lane >> 4;
  const unsigned short* ap  = Ahi + (size_t)(m0 + r16) * KA + quad * 8;
  const unsigned short* alp = Alo + (size_t)(m0 + r16) * KA + quad * 8;
  const unsigned short* bp  = Whi + (size_t)(n0 + r16) * KA + quad * 8;
  const unsigned short* blp = Wlo + (size_t)(n0 + r16) * KA + quad * 8;
  f32x4 acc = {0.f, 0.f, 0.f, 0.f};
  for (int k = 0; k < KA; k += 32) {
    bf16x8 a  = *(const bf16x8*)(ap + k);
    bf16x8 al = *(const bf16x8*)(alp + k);
    bf16x8 b  = *(const bf16x8*)(bp + k);
    bf16x8 bl = *(const bf16x8*)(blp + k);
    acc = __builtin_amdgcn_mfma_f32_16x16x32_bf16(a,  b,  acc, 0, 0, 0);
    acc = __builtin_amdgcn_mfma_f32_16x16x32_bf16(a,  bl, acc, 0, 0, 0);
    acc = __builtin_amdgcn_mfma_f32_16x16x32_bf16(al, b,  acc, 0, 0, 0);
  }
  #pragma unroll
  for (int r = 0; r < 4; ++r)
    gates[(size_t)(m0 + quad * 4 + r) * FOURD + n0 + r16] = acc[r];
}

// ---- LSTM pointwise: gate order i,f,g,o ----------------------------------
__global__ __launch_bounds__(256) void lstm_pointwise(const float* __restrict__ gates,
                                                      const float* __restrict__ bias,
                                                      float* __restrict__ h,
                                                      float* __restrict__ c,
                                                      unsigned short* __restrict__ Ahi,
                                                      unsigned short* __restrict__ Alo,
                                                      float* __restrict__ qout) {
  int idx = blockIdx.x * 256 + threadIdx.x;      // B*D
  int b = idx >> 8, d = idx & 255;
  const float* g = gates + (size_t)b * FOURD;
  float gi = g[d]       + bias[d];
  float gf = g[256 + d] + bias[256 + d];
  float gg = g[512 + d] + bias[512 + d];
  float go = g[768 + d] + bias[768 + d];
  float ig = 1.f / (1.f + expf(-gi));
  float fg = 1.f / (1.f + expf(-gf));
  float gt = tanhf(gg);
  float og = 1.f / (1.f + expf(-go));
  float cn = fg * c[idx] + ig * gt;
  float hn = og * tanhf(cn);
  c[idx] = cn; h[idx] = hn;
  unsigned short hi, lo; split_bf(hn, hi, lo);
  size_t ro = (size_t)b * KA;
  Ahi[ro + d] = hi;        Alo[ro + d] = lo;        // q_star q-part [0,256)
  Ahi[ro + 512 + d] = hi;  Alo[ro + 512 + d] = lo;  // h-part [512,768)
  qout[(size_t)b * 512 + d] = hn;                   // output q half
}

// ---- fused attention: one pass over x, online softmax --------------------
// Block per segment, 4 waves. Wave w streams nodes s+w, s+w+4, ... with its
// OWN online state (m, l, v[4]/lane); dot via 64-lane xor-shuffle butterfly;
// x row stays in registers for the weighted accumulate. Merge 4 partials at
// the end (flash-attention style). No cross-wave sync inside the loop.
__global__ __launch_bounds__(256) void attn_fused(const float* __restrict__ x,
                                                  const int* __restrict__ segs,
                                                  const float* __restrict__ h,
                                                  unsigned short* __restrict__ Ahi,
                                                  unsigned short* __restrict__ Alo,
                                                  float* __restrict__ qout) {
  int b = blockIdx.x;
  int t = threadIdx.x;
  int w = t >> 6, lane = t & 63;
  int s = segs[b], tend = segs[b + 1];

  float4 q = *(const float4*)(h + (size_t)b * DD + lane * 4);

  float m = -3.402823466e38f;   // acts as -inf
  float l = 0.f;
  float4 v = {0.f, 0.f, 0.f, 0.f};

  int i = s + w;
  float4 xv = {0.f, 0.f, 0.f, 0.f};
  if (i < tend) xv = *(const float4*)(x + (size_t)i * DD + lane * 4);
  for (; i < tend; i += 4) {
    float4 cur = xv;
    int nx = i + 4;
    if (nx < tend) xv = *(const float4*)(x + (size_t)nx * DD + lane * 4);
    float d = cur.x * q.x + cur.y * q.y + cur.z * q.z + cur.w * q.w;
    #pragma unroll
    for (int off = 32; off; off >>= 1) d += __shfl_xor(d, off);
    float mn = fmaxf(m, d);
    float alpha = __expf(m - mn);      // first iter: exp(-inf)=0
    float wgt   = __expf(d - mn);
    l = l * alpha + wgt;
    v.x = v.x * alpha + wgt * cur.x;
    v.y = v.y * alpha + wgt * cur.y;
    v.z = v.z * alpha + wgt * cur.z;
    v.w = v.w * alpha + wgt * cur.w;
    m = mn;
  }

  __shared__ float sm[4], sl[4];
  __shared__ float sv[4][DD];
  if (lane == 0) { sm[w] = m; sl[w] = l; }
  *(float4*)(&sv[w][lane * 4]) = v;
  __syncthreads();

  // thread t finalizes channel t
  float M = fmaxf(fmaxf(sm[0], sm[1]), fmaxf(sm[2], sm[3]));
  if (M < -1e37f) M = 0.f;             // mirror reference isfinite guard
  float a0 = __expf(sm[0] - M), a1 = __expf(sm[1] - M);
  float a2 = __expf(sm[2] - M), a3 = __expf(sm[3] - M);
  float L = sl[0] * a0 + sl[1] * a1 + sl[2] * a2 + sl[3] * a3;
  float r = (sv[0][t] * a0 + sv[1][t] * a1 + sv[2][t] * a2 + sv[3][t] * a3)
            / (L + 1e-16f);

  unsigned short hi, lo; split_bf(r, hi, lo);
  size_t ro = (size_t)b * KA;
  Ahi[ro + DD + t] = hi;  Alo[ro + DD + t] = lo;    // q_star r-part [256,512)
  qout[(size_t)b * 512 + DD + t] = r;               // output r half
}

// ---- launch --------------------------------------------------------------
extern "C" void kernel_launch(void* const* d_in, const int* in_sizes, int n_in,
                              void* d_out, int out_size, void* d_ws, size_t ws_size,
                              hipStream_t stream) {
  const float* x    = (const float*)d_in[0];
  const int*   batc = (const int*)d_in[2];
  const float* qst  = (const float*)d_in[3];
  const float* Wih  = (const float*)d_in[4];
  const float* Whh  = (const float*)d_in[5];
  const float* bih  = (const float*)d_in[6];
  const float* bhh  = (const float*)d_in[7];
  float* out = (float*)d_out;

  char* ws = (char*)d_ws;
  size_t off = 0;
  auto alloc = [&](size_t bytes) -> void* {
    void* p = ws + off; off = (off + bytes + 255) & ~(size_t)255; return p;
  };
  int*            segs = (int*)alloc((size_t)(BSEG + 1) * 4);
  unsigned short* Whi  = (unsigned short*)alloc((size_t)FOURD * KA * 2);
  unsigned short* Wlo  = (unsigned short*)alloc((size_t)FOURD * KA * 2);
  unsigned short* Ahi  = (unsigned short*)alloc((size_t)BSEG * KA * 2);
  unsigned short* Alo  = (unsigned short*)alloc((size_t)BSEG * KA * 2);
  float*          gate = (float*)alloc((size_t)BSEG * FOURD * 4);
  float*          h    = (float*)alloc((size_t)BSEG * DD * 4);
  float*          c    = (float*)alloc((size_t)BSEG * DD * 4);
  float*          bias = (float*)alloc((size_t)FOURD * 4);

  seg_bounds<<<5, 256, 0, stream>>>(batc, segs);
  prep_wcat<<<(FOURD * KA + 255) / 256, 256, 0, stream>>>(Wih, Whh, bih, bhh, Whi, Wlo, bias);
  prep_A<<<(BSEG * KA + 255) / 256, 256, 0, stream>>>(qst, Ahi, Alo, h, c);

  for (int step = 0; step < 3; ++step) {
    gemm_gates<<<1024, 256, 0, stream>>>(Ahi, Alo, Whi, Wlo, gate);
    lstm_pointwise<<<BSEG * DD / 256, 256, 0, stream>>>(gate, bias, h, c, Ahi, Alo, out);
    attn_fused<<<BSEG, 256, 0, stream>>>(x, segs, h, Ahi, Alo, out);
  }
}

// Round 5
// 447.040 us; speedup vs baseline: 1.4616x; 1.1757x over previous
//
#include <hip/hip_runtime.h>
#include <hip/hip_bf16.h>
#include <cstdint>

// Set2Set forward, 3 steps. N=200000, B=1024 segments, D=256. All f32 I/O.
// Round 5: (a) LDS-tiled GEMM (128x32 blocks, XOR-swizzled W staging,
// conflict-free), (b) LSTM pointwise fused into attention (block b only
// needs h_b), (c) single prep kernel. 7 launches total.

#define NN     200000
#define BSEG   1024
#define DD     256
#define KA     768     // 2D (q_star) + D (h)
#define FOURD  1024

using bf16x8 = __attribute__((ext_vector_type(8))) __bf16;
using f32x4  = __attribute__((ext_vector_type(4))) float;

__device__ __forceinline__ float bf2f(unsigned int u) {
  union { unsigned int i; float f; } v; v.i = (u & 0xffffu) << 16; return v.f;
}
__device__ __forceinline__ unsigned short f2bf(float f) {
  union { float f; unsigned int i; } v; v.f = f;
  unsigned int x = v.i;
  if ((x & 0x7fffffffu) > 0x7f800000u) return (unsigned short)((x >> 16) | 0x40);
  return (unsigned short)((x + 0x7fffu + ((x >> 16) & 1u)) >> 16);
}
__device__ __forceinline__ void split_bf(float f, unsigned short& hi, unsigned short& lo) {
  hi = f2bf(f);
  lo = f2bf(f - bf2f(hi));
}

// ---- combined prep: seg bounds + W split + A init + c=0 ------------------
__global__ void prep_all(const int* __restrict__ batch, int* __restrict__ segs,
                         const float* __restrict__ Wih, const float* __restrict__ Whh,
                         const float* __restrict__ bih, const float* __restrict__ bhh,
                         unsigned short* __restrict__ Whi, unsigned short* __restrict__ Wlo,
                         float* __restrict__ bias,
                         const float* __restrict__ qst,
                         unsigned short* __restrict__ Ahi, unsigned short* __restrict__ Alo,
                         float* __restrict__ c) {
  int idx = blockIdx.x * 256 + threadIdx.x;       // grid covers 786432
  if (idx <= BSEG) {
    int lo = 0, hi = NN;
    while (lo < hi) { int mid = (lo + hi) >> 1; if (batch[mid] < idx) lo = mid + 1; else hi = mid; }
    segs[idx] = lo;
  }
  if (idx < FOURD) bias[idx] = bih[idx] + bhh[idx];
  if (idx < FOURD * KA) {
    int j = idx / KA, k = idx - j * KA;
    float w = (k < 512) ? Wih[j * 512 + k] : Whh[j * 256 + (k - 512)];
    unsigned short hi, lo; split_bf(w, hi, lo);
    Whi[idx] = hi; Wlo[idx] = lo;
  }
  if (idx < BSEG * KA) {
    int b = idx / KA, k = idx - b * KA;
    unsigned short hi = 0, lo = 0;
    if (k < 512) split_bf(qst[b * 512 + k], hi, lo);
    Ahi[idx] = hi; Alo[idx] = lo;
  }
  if (idx < BSEG * DD) c[idx] = 0.f;
}

// ---- LSTM gates GEMM: gates = (Ahi+Alo) @ (Whi+Wlo)^T --------------------
// 256 blocks, each 128 rows x 32 cols. W chunk (32 x 64k, hi+lo) staged in
// LDS with XOR swizzle (row stride 64 elems = 32 banks; col-block ^= row&7
// -> conflict-free b128 reads & writes). A read direct from global.
// Frags: A[m=lane&15][k=quad*8+j]; B(B^T)=W[n=lane&15][k=quad*8+j];
// D: col=lane&15, row=quad*4+r.
__global__ __launch_bounds__(256) void gemm_gates(const unsigned short* __restrict__ Ahi,
                                                  const unsigned short* __restrict__ Alo,
                                                  const unsigned short* __restrict__ Whi,
                                                  const unsigned short* __restrict__ Wlo,
                                                  float* __restrict__ gates) {
  int bx = blockIdx.x;
  int m0 = (bx >> 5) << 7;      // * 128
  int n0 = (bx & 31) << 5;      // * 32
  int t = threadIdx.x, w = t >> 6, lane = t & 63;
  int r16 = lane & 15, quad = lane >> 4;

  __shared__ unsigned short sWhi[32 * 64];
  __shared__ unsigned short sWlo[32 * 64];

  f32x4 acc[2][2] = {};

  const unsigned short* a0h = Ahi + (size_t)(m0 + 32 * w + r16) * KA + quad * 8;
  const unsigned short* a0l = Alo + (size_t)(m0 + 32 * w + r16) * KA + quad * 8;

  int srow = t >> 3;            // 0..31
  int scb  = t & 7;             // 0..7 col-block (8 bf16 each)
  const unsigned short* gwh = Whi + (size_t)(n0 + srow) * KA + scb * 8;
  const unsigned short* gwl = Wlo + (size_t)(n0 + srow) * KA + scb * 8;
  int sdst = srow * 64 + ((scb ^ (srow & 7)) * 8);

  for (int kc = 0; kc < KA; kc += 64) {
    __syncthreads();
    *(bf16x8*)&sWhi[sdst] = *(const bf16x8*)(gwh + kc);
    *(bf16x8*)&sWlo[sdst] = *(const bf16x8*)(gwl + kc);
    __syncthreads();
    #pragma unroll
    for (int ks = 0; ks < 2; ++ks) {
      bf16x8 bh[2], bl[2];
      #pragma unroll
      for (int ni = 0; ni < 2; ++ni) {
        int wr = 16 * ni + r16;
        int off = wr * 64 + (((ks * 4 + quad) ^ (wr & 7)) * 8);
        bh[ni] = *(const bf16x8*)&sWhi[off];
        bl[ni] = *(const bf16x8*)&sWlo[off];
      }
      #pragma unroll
      for (int ms = 0; ms < 2; ++ms) {
        bf16x8 a  = *(const bf16x8*)(a0h + (size_t)ms * 16 * KA + kc + ks * 32);
        bf16x8 al = *(const bf16x8*)(a0l + (size_t)ms * 16 * KA + kc + ks * 32);
        #pragma unroll
        for (int ni = 0; ni < 2; ++ni) {
          acc[ms][ni] = __builtin_amdgcn_mfma_f32_16x16x32_bf16(a,  bh[ni], acc[ms][ni], 0, 0, 0);
          acc[ms][ni] = __builtin_amdgcn_mfma_f32_16x16x32_bf16(a,  bl[ni], acc[ms][ni], 0, 0, 0);
          acc[ms][ni] = __builtin_amdgcn_mfma_f32_16x16x32_bf16(al, bh[ni], acc[ms][ni], 0, 0, 0);
        }
      }
    }
  }
  #pragma unroll
  for (int ms = 0; ms < 2; ++ms)
    #pragma unroll
    for (int ni = 0; ni < 2; ++ni)
      #pragma unroll
      for (int r = 0; r < 4; ++r)
        gates[(size_t)(m0 + 32 * w + 16 * ms + quad * 4 + r) * FOURD
              + n0 + 16 * ni + r16] = acc[ms][ni][r];
}

// ---- fused LSTM-pointwise + one-pass online-softmax attention ------------
// Block b: compute h_b from gates row b (only this block needs it), keep in
// LDS, then stream segment b's x rows once with per-wave online softmax
// state; merge 4 wave-partials at the end.
__global__ __launch_bounds__(256) void attn_fused(const float* __restrict__ x,
                                                  const int* __restrict__ segs,
                                                  const float* __restrict__ gates,
                                                  const float* __restrict__ bias,
                                                  float* __restrict__ c,
                                                  unsigned short* __restrict__ Ahi,
                                                  unsigned short* __restrict__ Alo,
                                                  float* __restrict__ qout) {
  int b = blockIdx.x, t = threadIdx.x;
  int w = t >> 6, lane = t & 63;

  // --- LSTM pointwise, channel t of row b (gate order i,f,g,o) ---
  const float* g = gates + (size_t)b * FOURD;
  float gi = g[t]       + bias[t];
  float gf = g[256 + t] + bias[256 + t];
  float gg = g[512 + t] + bias[512 + t];
  float go = g[768 + t] + bias[768 + t];
  float ig = 1.f / (1.f + expf(-gi));
  float fg = 1.f / (1.f + expf(-gf));
  float gt = tanhf(gg);
  float og = 1.f / (1.f + expf(-go));
  int cidx = b * DD + t;
  float cn = fg * c[cidx] + ig * gt;
  c[cidx] = cn;
  float hn = og * tanhf(cn);

  __shared__ __align__(16) float sh[DD];
  sh[t] = hn;
  {
    unsigned short hi, lo; split_bf(hn, hi, lo);
    size_t ro = (size_t)b * KA;
    Ahi[ro + t] = hi;        Alo[ro + t] = lo;        // q-part [0,256)
    Ahi[ro + 512 + t] = hi;  Alo[ro + 512 + t] = lo;  // h-part [512,768)
    qout[(size_t)b * 512 + t] = hn;                   // output q half
  }
  __syncthreads();

  // --- attention over segment b ---
  int s = segs[b], tend = segs[b + 1];
  float4 q = *(const float4*)(sh + lane * 4);

  float m = -3.402823466e38f;
  float l = 0.f;
  float4 v = {0.f, 0.f, 0.f, 0.f};

  int i = s + w;
  float4 xv = {0.f, 0.f, 0.f, 0.f};
  if (i < tend) xv = *(const float4*)(x + (size_t)i * DD + lane * 4);
  for (; i < tend; i += 4) {
    float4 cur = xv;
    int nx = i + 4;
    if (nx < tend) xv = *(const float4*)(x + (size_t)nx * DD + lane * 4);
    float d = cur.x * q.x + cur.y * q.y + cur.z * q.z + cur.w * q.w;
    #pragma unroll
    for (int off = 32; off; off >>= 1) d += __shfl_xor(d, off);
    float mn = fmaxf(m, d);
    float alpha = __expf(m - mn);
    float wgt   = __expf(d - mn);
    l = l * alpha + wgt;
    v.x = v.x * alpha + wgt * cur.x;
    v.y = v.y * alpha + wgt * cur.y;
    v.z = v.z * alpha + wgt * cur.z;
    v.w = v.w * alpha + wgt * cur.w;
    m = mn;
  }

  __shared__ float sm[4], sl[4];
  __shared__ __align__(16) float sv[4][DD];
  if (lane == 0) { sm[w] = m; sl[w] = l; }
  *(float4*)(&sv[w][lane * 4]) = v;
  __syncthreads();

  float M = fmaxf(fmaxf(sm[0], sm[1]), fmaxf(sm[2], sm[3]));
  if (M < -1e37f) M = 0.f;             // mirror reference isfinite guard
  float a0 = __expf(sm[0] - M), a1 = __expf(sm[1] - M);
  float a2 = __expf(sm[2] - M), a3 = __expf(sm[3] - M);
  float L = sl[0] * a0 + sl[1] * a1 + sl[2] * a2 + sl[3] * a3;
  float r = (sv[0][t] * a0 + sv[1][t] * a1 + sv[2][t] * a2 + sv[3][t] * a3)
            / (L + 1e-16f);

  unsigned short hi, lo; split_bf(r, hi, lo);
  size_t ro = (size_t)b * KA;
  Ahi[ro + DD + t] = hi;  Alo[ro + DD + t] = lo;    // r-part [256,512)
  qout[(size_t)b * 512 + DD + t] = r;               // output r half
}

// ---- launch --------------------------------------------------------------
extern "C" void kernel_launch(void* const* d_in, const int* in_sizes, int n_in,
                              void* d_out, int out_size, void* d_ws, size_t ws_size,
                              hipStream_t stream) {
  const float* x    = (const float*)d_in[0];
  const int*   batc = (const int*)d_in[2];
  const float* qst  = (const float*)d_in[3];
  const float* Wih  = (const float*)d_in[4];
  const float* Whh  = (const float*)d_in[5];
  const float* bih  = (const float*)d_in[6];
  const float* bhh  = (const float*)d_in[7];
  float* out = (float*)d_out;

  char* ws = (char*)d_ws;
  size_t off = 0;
  auto alloc = [&](size_t bytes) -> void* {
    void* p = ws + off; off = (off + bytes + 255) & ~(size_t)255; return p;
  };
  int*            segs = (int*)alloc((size_t)(BSEG + 1) * 4);
  unsigned short* Whi  = (unsigned short*)alloc((size_t)FOURD * KA * 2);
  unsigned short* Wlo  = (unsigned short*)alloc((size_t)FOURD * KA * 2);
  unsigned short* Ahi  = (unsigned short*)alloc((size_t)BSEG * KA * 2);
  unsigned short* Alo  = (unsigned short*)alloc((size_t)BSEG * KA * 2);
  float*          gate = (float*)alloc((size_t)BSEG * FOURD * 4);
  float*          c    = (float*)alloc((size_t)BSEG * DD * 4);
  float*          bias = (float*)alloc((size_t)FOURD * 4);

  prep_all<<<(FOURD * KA + 255) / 256, 256, 0, stream>>>(
      batc, segs, Wih, Whh, bih, bhh, Whi, Wlo, bias, qst, Ahi, Alo, c);

  for (int step = 0; step < 3; ++step) {
    gemm_gates<<<256, 256, 0, stream>>>(Ahi, Alo, Whi, Wlo, gate);
    attn_fused<<<BSEG, 256, 0, stream>>>(x, segs, gate, bias, c, Ahi, Alo, out);
  }
}

// Round 6
// 426.071 us; speedup vs baseline: 1.5335x; 1.0492x over previous
//
#include <hip/hip_runtime.h>
#include <hip/hip_bf16.h>
#include <cstdint>

// Set2Set forward, 3 steps. N=200000, B=1024 segments, D=256. All f32 I/O.
// Round 6: K reduced 768->512 by exploiting q==h after step 0:
//   step 0:  gates = q_star . W_ih^T                    (A=[q_star], W1=W_ih)
//   steps1+: gates = [h|r] . [W_ih_q + W_hh | W_ih_r]^T (A=[h|r],   W2 merged)
// GEMM: 256 blocks of 128x32, XOR-swizzled LDS W staging, bf16 hi/lo
// compensated MFMA (3 mfma/k-step). Attention: fused LSTM-pointwise +
// one-pass online softmax (per-wave state, merge at end).

#define NN     200000
#define BSEG   1024
#define DD     256
#define KA     512     // collapsed K
#define FOURD  1024

using bf16x8 = __attribute__((ext_vector_type(8))) __bf16;
using f32x4  = __attribute__((ext_vector_type(4))) float;

__device__ __forceinline__ float bf2f(unsigned int u) {
  union { unsigned int i; float f; } v; v.i = (u & 0xffffu) << 16; return v.f;
}
__device__ __forceinline__ unsigned short f2bf(float f) {
  union { float f; unsigned int i; } v; v.f = f;
  unsigned int x = v.i;
  if ((x & 0x7fffffffu) > 0x7f800000u) return (unsigned short)((x >> 16) | 0x40);
  return (unsigned short)((x + 0x7fffu + ((x >> 16) & 1u)) >> 16);
}
__device__ __forceinline__ void split_bf(float f, unsigned short& hi, unsigned short& lo) {
  hi = f2bf(f);
  lo = f2bf(f - bf2f(hi));
}

// ---- combined prep: seg bounds + W1/W2 split + A init + c=0 --------------
__global__ void prep_all(const int* __restrict__ batch, int* __restrict__ segs,
                         const float* __restrict__ Wih, const float* __restrict__ Whh,
                         const float* __restrict__ bih, const float* __restrict__ bhh,
                         unsigned short* __restrict__ W1hi, unsigned short* __restrict__ W1lo,
                         unsigned short* __restrict__ W2hi, unsigned short* __restrict__ W2lo,
                         float* __restrict__ bias,
                         const float* __restrict__ qst,
                         unsigned short* __restrict__ Ahi, unsigned short* __restrict__ Alo,
                         float* __restrict__ c) {
  int idx = blockIdx.x * 256 + threadIdx.x;       // grid covers 524288
  if (idx <= BSEG) {
    int lo = 0, hi = NN;
    while (lo < hi) { int mid = (lo + hi) >> 1; if (batch[mid] < idx) lo = mid + 1; else hi = mid; }
    segs[idx] = lo;
  }
  if (idx < FOURD) bias[idx] = bih[idx] + bhh[idx];
  if (idx < FOURD * KA) {
    int j = idx / KA, k = idx - j * KA;
    float w1 = Wih[j * 512 + k];
    float w2 = (k < 256) ? (Wih[j * 512 + k] + Whh[j * 256 + k])
                         : Wih[j * 512 + k];
    unsigned short hi, lo;
    split_bf(w1, hi, lo); W1hi[idx] = hi; W1lo[idx] = lo;
    split_bf(w2, hi, lo); W2hi[idx] = hi; W2lo[idx] = lo;
  }
  if (idx < BSEG * KA) {
    unsigned short hi, lo; split_bf(qst[idx], hi, lo);
    Ahi[idx] = hi; Alo[idx] = lo;
  }
  if (idx < BSEG * DD) c[idx] = 0.f;
}

// ---- LSTM gates GEMM: gates = (Ahi+Alo) @ (Whi+Wlo)^T, K=512 -------------
// 256 blocks, each 128 rows x 32 cols. W chunk (32 x 64k, hi+lo) staged in
// LDS with XOR swizzle (row stride 64 elems = 32 banks; col-block ^= row&7
// -> conflict-free b128 reads & writes). A read direct from global.
// Frags: A[m=lane&15][k=quad*8+j]; B(B^T)=W[n=lane&15][k=quad*8+j];
// D: col=lane&15, row=quad*4+r.
__global__ __launch_bounds__(256) void gemm_gates(const unsigned short* __restrict__ Ahi,
                                                  const unsigned short* __restrict__ Alo,
                                                  const unsigned short* __restrict__ Whi,
                                                  const unsigned short* __restrict__ Wlo,
                                                  float* __restrict__ gates) {
  int bx = blockIdx.x;
  int m0 = (bx >> 5) << 7;      // * 128
  int n0 = (bx & 31) << 5;      // * 32
  int t = threadIdx.x, w = t >> 6, lane = t & 63;
  int r16 = lane & 15, quad = lane >> 4;

  __shared__ unsigned short sWhi[32 * 64];
  __shared__ unsigned short sWlo[32 * 64];

  f32x4 acc[2][2] = {};

  const unsigned short* a0h = Ahi + (size_t)(m0 + 32 * w + r16) * KA + quad * 8;
  const unsigned short* a0l = Alo + (size_t)(m0 + 32 * w + r16) * KA + quad * 8;

  int srow = t >> 3;            // 0..31
  int scb  = t & 7;             // 0..7 col-block (8 bf16 each)
  const unsigned short* gwh = Whi + (size_t)(n0 + srow) * KA + scb * 8;
  const unsigned short* gwl = Wlo + (size_t)(n0 + srow) * KA + scb * 8;
  int sdst = srow * 64 + ((scb ^ (srow & 7)) * 8);

  for (int kc = 0; kc < KA; kc += 64) {
    __syncthreads();
    *(bf16x8*)&sWhi[sdst] = *(const bf16x8*)(gwh + kc);
    *(bf16x8*)&sWlo[sdst] = *(const bf16x8*)(gwl + kc);
    __syncthreads();
    #pragma unroll
    for (int ks = 0; ks < 2; ++ks) {
      bf16x8 bh[2], bl[2];
      #pragma unroll
      for (int ni = 0; ni < 2; ++ni) {
        int wr = 16 * ni + r16;
        int off = wr * 64 + (((ks * 4 + quad) ^ (wr & 7)) * 8);
        bh[ni] = *(const bf16x8*)&sWhi[off];
        bl[ni] = *(const bf16x8*)&sWlo[off];
      }
      #pragma unroll
      for (int ms = 0; ms < 2; ++ms) {
        bf16x8 a  = *(const bf16x8*)(a0h + (size_t)ms * 16 * KA + kc + ks * 32);
        bf16x8 al = *(const bf16x8*)(a0l + (size_t)ms * 16 * KA + kc + ks * 32);
        #pragma unroll
        for (int ni = 0; ni < 2; ++ni) {
          acc[ms][ni] = __builtin_amdgcn_mfma_f32_16x16x32_bf16(a,  bh[ni], acc[ms][ni], 0, 0, 0);
          acc[ms][ni] = __builtin_amdgcn_mfma_f32_16x16x32_bf16(a,  bl[ni], acc[ms][ni], 0, 0, 0);
          acc[ms][ni] = __builtin_amdgcn_mfma_f32_16x16x32_bf16(al, bh[ni], acc[ms][ni], 0, 0, 0);
        }
      }
    }
  }
  #pragma unroll
  for (int ms = 0; ms < 2; ++ms)
    #pragma unroll
    for (int ni = 0; ni < 2; ++ni)
      #pragma unroll
      for (int r = 0; r < 4; ++r)
        gates[(size_t)(m0 + 32 * w + 16 * ms + quad * 4 + r) * FOURD
              + n0 + 16 * ni + r16] = acc[ms][ni][r];
}

// ---- fused LSTM-pointwise + one-pass online-softmax attention ------------
// Block b: compute h_b from gates row b (only this block needs it), keep in
// LDS, then stream segment b's x rows once with per-wave online softmax
// state; merge 4 wave-partials at the end. A (next GEMM input) = [h | r].
__global__ __launch_bounds__(256) void attn_fused(const float* __restrict__ x,
                                                  const int* __restrict__ segs,
                                                  const float* __restrict__ gates,
                                                  const float* __restrict__ bias,
                                                  float* __restrict__ c,
                                                  unsigned short* __restrict__ Ahi,
                                                  unsigned short* __restrict__ Alo,
                                                  float* __restrict__ qout) {
  int b = blockIdx.x, t = threadIdx.x;
  int w = t >> 6, lane = t & 63;

  // --- LSTM pointwise, channel t of row b (gate order i,f,g,o) ---
  const float* g = gates + (size_t)b * FOURD;
  float gi = g[t]       + bias[t];
  float gf = g[256 + t] + bias[256 + t];
  float gg = g[512 + t] + bias[512 + t];
  float go = g[768 + t] + bias[768 + t];
  float ig = 1.f / (1.f + expf(-gi));
  float fg = 1.f / (1.f + expf(-gf));
  float gt = tanhf(gg);
  float og = 1.f / (1.f + expf(-go));
  int cidx = b * DD + t;
  float cn = fg * c[cidx] + ig * gt;
  c[cidx] = cn;
  float hn = og * tanhf(cn);

  __shared__ __align__(16) float sh[DD];
  sh[t] = hn;
  {
    unsigned short hi, lo; split_bf(hn, hi, lo);
    size_t ro = (size_t)b * KA;
    Ahi[ro + t] = hi;  Alo[ro + t] = lo;             // h-part [0,256)
    qout[(size_t)b * 512 + t] = hn;                  // output q half
  }
  __syncthreads();

  // --- attention over segment b ---
  int s = segs[b], tend = segs[b + 1];
  float4 q = *(const float4*)(sh + lane * 4);

  float m = -3.402823466e38f;
  float l = 0.f;
  float4 v = {0.f, 0.f, 0.f, 0.f};

  int i = s + w;
  float4 xv = {0.f, 0.f, 0.f, 0.f};
  if (i < tend) xv = *(const float4*)(x + (size_t)i * DD + lane * 4);
  for (; i < tend; i += 4) {
    float4 cur = xv;
    int nx = i + 4;
    if (nx < tend) xv = *(const float4*)(x + (size_t)nx * DD + lane * 4);
    float d = cur.x * q.x + cur.y * q.y + cur.z * q.z + cur.w * q.w;
    #pragma unroll
    for (int off = 32; off; off >>= 1) d += __shfl_xor(d, off);
    float mn = fmaxf(m, d);
    float alpha = __expf(m - mn);
    float wgt   = __expf(d - mn);
    l = l * alpha + wgt;
    v.x = v.x * alpha + wgt * cur.x;
    v.y = v.y * alpha + wgt * cur.y;
    v.z = v.z * alpha + wgt * cur.z;
    v.w = v.w * alpha + wgt * cur.w;
    m = mn;
  }

  __shared__ float sm[4], sl[4];
  __shared__ __align__(16) float sv[4][DD];
  if (lane == 0) { sm[w] = m; sl[w] = l; }
  *(float4*)(&sv[w][lane * 4]) = v;
  __syncthreads();

  float M = fmaxf(fmaxf(sm[0], sm[1]), fmaxf(sm[2], sm[3]));
  if (M < -1e37f) M = 0.f;             // mirror reference isfinite guard
  float a0 = __expf(sm[0] - M), a1 = __expf(sm[1] - M);
  float a2 = __expf(sm[2] - M), a3 = __expf(sm[3] - M);
  float L = sl[0] * a0 + sl[1] * a1 + sl[2] * a2 + sl[3] * a3;
  float r = (sv[0][t] * a0 + sv[1][t] * a1 + sv[2][t] * a2 + sv[3][t] * a3)
            / (L + 1e-16f);

  unsigned short hi, lo; split_bf(r, hi, lo);
  size_t ro = (size_t)b * KA;
  Ahi[ro + DD + t] = hi;  Alo[ro + DD + t] = lo;    // r-part [256,512)
  qout[(size_t)b * 512 + DD + t] = r;               // output r half
}

// ---- launch --------------------------------------------------------------
extern "C" void kernel_launch(void* const* d_in, const int* in_sizes, int n_in,
                              void* d_out, int out_size, void* d_ws, size_t ws_size,
                              hipStream_t stream) {
  const float* x    = (const float*)d_in[0];
  const int*   batc = (const int*)d_in[2];
  const float* qst  = (const float*)d_in[3];
  const float* Wih  = (const float*)d_in[4];
  const float* Whh  = (const float*)d_in[5];
  const float* bih  = (const float*)d_in[6];
  const float* bhh  = (const float*)d_in[7];
  float* out = (float*)d_out;

  char* ws = (char*)d_ws;
  size_t off = 0;
  auto alloc = [&](size_t bytes) -> void* {
    void* p = ws + off; off = (off + bytes + 255) & ~(size_t)255; return p;
  };
  int*            segs = (int*)alloc((size_t)(BSEG + 1) * 4);
  unsigned short* W1hi = (unsigned short*)alloc((size_t)FOURD * KA * 2);
  unsigned short* W1lo = (unsigned short*)alloc((size_t)FOURD * KA * 2);
  unsigned short* W2hi = (unsigned short*)alloc((size_t)FOURD * KA * 2);
  unsigned short* W2lo = (unsigned short*)alloc((size_t)FOURD * KA * 2);
  unsigned short* Ahi  = (unsigned short*)alloc((size_t)BSEG * KA * 2);
  unsigned short* Alo  = (unsigned short*)alloc((size_t)BSEG * KA * 2);
  float*          gate = (float*)alloc((size_t)BSEG * FOURD * 4);
  float*          c    = (float*)alloc((size_t)BSEG * DD * 4);
  float*          bias = (float*)alloc((size_t)FOURD * 4);

  prep_all<<<(FOURD * KA + 255) / 256, 256, 0, stream>>>(
      batc, segs, Wih, Whh, bih, bhh, W1hi, W1lo, W2hi, W2lo, bias, qst, Ahi, Alo, c);

  for (int step = 0; step < 3; ++step) {
    const unsigned short* whi = step ? W2hi : W1hi;
    const unsigned short* wlo = step ? W2lo : W1lo;
    gemm_gates<<<256, 256, 0, stream>>>(Ahi, Alo, whi, wlo, gate);
    attn_fused<<<BSEG, 256, 0, stream>>>(x, segs, gate, bias, c, Ahi, Alo, out);
  }
}